// Round 1
// baseline (841.553 us; speedup 1.0000x reference)
//
#include <hip/hip_runtime.h>
#include <hip/hip_bf16.h>

#define D_MODEL 1024
#define N_HEADS 16
#define HEAD_DIM 64
#define D_FF 4096
#define SEQ 2048
#define BATCH 4
#define NTOK (BATCH*SEQ)

typedef __attribute__((ext_vector_type(4))) float  f32x4;
typedef __attribute__((ext_vector_type(8))) short  s16x8;
typedef __attribute__((ext_vector_type(4))) unsigned short u16x4;

typedef __attribute__((address_space(1))) const unsigned int gas_u32;
typedef __attribute__((address_space(3))) unsigned int las_u32;

__device__ __forceinline__ void gload_lds16(const void* g, void* l) {
  __builtin_amdgcn_global_load_lds((gas_u32*)g, (las_u32*)l, 16, 0, 0);
}

__device__ __forceinline__ float bf2f(unsigned short u) {
  union { unsigned int i; float f; } v; v.i = ((unsigned int)u) << 16; return v.f;
}
__device__ __forceinline__ unsigned short f2bf(float f) {
  union { float f; unsigned int i; } v; v.f = f;
  return (unsigned short)((v.i + 0x7fffu + ((v.i >> 16) & 1u)) >> 16);
}

// ---------------- fp32 -> bf16 weight/activation convert ----------------
__global__ __launch_bounds__(256) void cvt_k(const float* __restrict__ in,
                                             unsigned short* __restrict__ out, int n) {
  for (long i = ((long)blockIdx.x*256 + threadIdx.x)*4; i < n; i += (long)gridDim.x*1024) {
    f32x4 v = *(const f32x4*)&in[i];
    u16x4 o;
    #pragma unroll
    for (int c=0;c<4;c++) o[c] = f2bf(v[c]);
    *(u16x4*)&out[i] = o;
  }
}

// ---------------- RoPE cos/sin tables: [SEQ][32] ----------------
__global__ __launch_bounds__(256) void rope_tables_k(const int* __restrict__ pos,
                                                     float* __restrict__ cosT,
                                                     float* __restrict__ sinT) {
  int idx = blockIdx.x*256 + threadIdx.x;      // SEQ*32 exact
  int t = idx >> 5, i = idx & 31;
  float p  = (float)pos[t];
  float fr = powf(10000.0f, -(float)i * (1.0f/32.0f));
  float ang = p * fr;
  cosT[idx] = cosf(ang);
  sinT[idx] = sinf(ang);
}

// ---------------- RMSNorm: fp32 in -> bf16 out, one row per block ----------------
__global__ __launch_bounds__(256) void rmsnorm_k(const float* __restrict__ x,
                                                 const float* __restrict__ wgt,
                                                 unsigned short* __restrict__ out) {
  const long row = blockIdx.x;
  const int t = threadIdx.x;
  f32x4 v = *(const f32x4*)&x[row*D_MODEL + t*4];
  float ss = v[0]*v[0] + v[1]*v[1] + v[2]*v[2] + v[3]*v[3];
  #pragma unroll
  for (int off=1; off<64; off<<=1) ss += __shfl_xor(ss, off, 64);
  __shared__ float red[4];
  if ((t & 63) == 0) red[t >> 6] = ss;
  __syncthreads();
  float tot = red[0] + red[1] + red[2] + red[3];
  float inv = rsqrtf(tot * (1.0f/D_MODEL) + 1e-5f);
  f32x4 wv = *(const f32x4*)&wgt[t*4];
  u16x4 o;
  #pragma unroll
  for (int c=0;c<4;c++) o[c] = f2bf(v[c] * inv * wv[c]);
  *(u16x4*)&out[row*D_MODEL + t*4] = o;
}

// ---------------- RoPE in-place on bf16 q,k ----------------
__global__ __launch_bounds__(256) void rope_k(unsigned short* __restrict__ q,
                                              unsigned short* __restrict__ k,
                                              const float* __restrict__ cosT,
                                              const float* __restrict__ sinT) {
  long idx = (long)blockIdx.x*256 + threadIdx.x;   // NTOK*16*8 exact
  int ig = (int)(idx & 7);
  long th = idx >> 3;
  int h = (int)(th & 15);
  long bt = th >> 4;
  int t = (int)(bt & (SEQ-1));
  long off = bt*D_MODEL + h*HEAD_DIM + ig*8;
  f32x4 cs = *(const f32x4*)&cosT[t*32 + ig*4];
  f32x4 sn = *(const f32x4*)&sinT[t*32 + ig*4];
  s16x8 qv = *(const s16x8*)&q[off];
  s16x8 kv = *(const s16x8*)&k[off];
  s16x8 qo, ko;
  #pragma unroll
  for (int p=0;p<4;p++) {
    float q1 = bf2f((unsigned short)qv[2*p]), q2 = bf2f((unsigned short)qv[2*p+1]);
    qo[2*p]   = (short)f2bf(q1*cs[p] - q2*sn[p]);
    qo[2*p+1] = (short)f2bf(q1*sn[p] + q2*cs[p]);
    float k1 = bf2f((unsigned short)kv[2*p]), k2 = bf2f((unsigned short)kv[2*p+1]);
    ko[2*p]   = (short)f2bf(k1*cs[p] - k2*sn[p]);
    ko[2*p+1] = (short)f2bf(k1*sn[p] + k2*cs[p]);
  }
  *(s16x8*)&q[off] = qo;
  *(s16x8*)&k[off] = ko;
}

// ---------------- GEMM: C[M,N] = A[M,K](bf16) * W[N,K]^T(bf16) ----------------
// 128x128 tile, BK=64, 4 waves (2x2), 4x4 16x16x32 frags/wave.
// LDS staged via global_load_lds with XOR chunk swizzle (inverse-swizzled source,
// swizzled ds_read) to avoid bank conflicts (rule 21 / T2).
// EPI 0: write bf16 C.  EPI 1: write fp32 C = resid + acc.
template<int EPI>
__global__ __launch_bounds__(256) void gemm_bt(const unsigned short* __restrict__ A,
                                               const unsigned short* __restrict__ W,
                                               unsigned short* __restrict__ Cb,
                                               float* __restrict__ Cf,
                                               const float* __restrict__ resid,
                                               int M, int N, int K) {
  __shared__ __align__(16) unsigned short As[128*64];
  __shared__ __align__(16) unsigned short Bs[128*64];

  const int nwg = gridDim.x * gridDim.y;
  int orig = blockIdx.y * gridDim.x + blockIdx.x;
  int swz = orig;
  if ((nwg & 7) == 0) {                 // bijective XCD swizzle
    int cpx = nwg >> 3;
    swz = (orig & 7) * cpx + (orig >> 3);
  }
  const int bx = swz % gridDim.x;
  const int by = swz / gridDim.x;

  const int tid = threadIdx.x;
  const int w  = tid >> 6;
  const int l  = tid & 63;
  const int lr = l & 15;
  const int lg = l >> 4;
  const int wm = (w >> 1) * 64;
  const int wn = (w & 1) * 64;

  const long rowA0 = (long)by * 128;
  const long rowB0 = (long)bx * 128;

  f32x4 acc[4][4] = {};

  for (int kt = 0; kt < K; kt += 64) {
    #pragma unroll
    for (int it = 0; it < 4; ++it) {       // stage A tile (128x64 bf16, 1024 chunks)
      int chunk = it*256 + tid;
      int row = chunk >> 3;
      int csw = (chunk & 7) ^ (row & 7);   // inverse-swizzled source chunk
      gload_lds16(&A[(rowA0 + row)*(long)K + kt + csw*8], &As[chunk*8]);
    }
    #pragma unroll
    for (int it = 0; it < 4; ++it) {       // stage B tile
      int chunk = it*256 + tid;
      int row = chunk >> 3;
      int csw = (chunk & 7) ^ (row & 7);
      gload_lds16(&W[(rowB0 + row)*(long)K + kt + csw*8], &Bs[chunk*8]);
    }
    __syncthreads();                       // drains vmcnt -> LDS ready

    s16x8 af[2][4], bfv[2][4];
    #pragma unroll
    for (int m=0;m<4;m++) {
      int row = wm + m*16 + lr;
      #pragma unroll
      for (int kk=0;kk<2;kk++) {
        int sw = (kk*4+lg) ^ (row & 7);    // swizzled read
        af[kk][m] = *(const s16x8*)&As[row*64 + sw*8];
      }
    }
    #pragma unroll
    for (int n=0;n<4;n++) {
      int row = wn + n*16 + lr;
      #pragma unroll
      for (int kk=0;kk<2;kk++) {
        int sw = (kk*4+lg) ^ (row & 7);
        bfv[kk][n] = *(const s16x8*)&Bs[row*64 + sw*8];
      }
    }
    #pragma unroll
    for (int kk=0;kk<2;kk++)
      #pragma unroll
      for (int m=0;m<4;m++)
        #pragma unroll
        for (int n=0;n<4;n++)
          acc[m][n] = __builtin_amdgcn_mfma_f32_16x16x32_bf16(af[kk][m], bfv[kk][n], acc[m][n], 0,0,0);
    __syncthreads();                       // all reads done before next stage
  }

  #pragma unroll
  for (int m=0;m<4;m++)
    #pragma unroll
    for (int n=0;n<4;n++)
      #pragma unroll
      for (int r=0;r<4;r++) {
        long row = rowA0 + wm + m*16 + lg*4 + r;
        long col = rowB0 + wn + n*16 + lr;
        float val = acc[m][n][r];
        if constexpr (EPI == 0) {
          Cb[row*(long)N + col] = f2bf(val);
        } else {
          Cf[row*(long)N + col] = resid[row*(long)N + col] + val;
        }
      }
}

// ---------------- Flash attention (causal), 64-row Q tile, 4 waves ----------------
__global__ __launch_bounds__(256) void attn_k(const unsigned short* __restrict__ Q,
                                              const unsigned short* __restrict__ K,
                                              const unsigned short* __restrict__ V,
                                              unsigned short* __restrict__ O) {
  const int bh = blockIdx.y;
  const int b = bh >> 4;
  const int h = bh & 15;
  const int q0 = blockIdx.x * 64;
  const int tid = threadIdx.x;
  const int w  = tid >> 6;
  const int l  = tid & 63;
  const int lr = l & 15;
  const int lg = l >> 4;

  __shared__ __align__(16) unsigned short Vt[64][72];      // V^T, padded
  __shared__ __align__(16) unsigned short P[4][16][72];    // per-wave P tiles

  const long rowQ = (long)(b*SEQ + q0 + w*16 + lr);
  s16x8 qf0 = *(const s16x8*)&Q[rowQ*D_MODEL + h*HEAD_DIM + lg*8];
  s16x8 qf1 = *(const s16x8*)&Q[rowQ*D_MODEL + h*HEAD_DIM + 32 + lg*8];

  float mi[4], li[4];
  f32x4 oa[4] = {};
  #pragma unroll
  for (int r=0;r<4;r++) { mi[r] = -1e30f; li[r] = 0.f; }

  const int ntile = blockIdx.x + 1;
  for (int t=0; t<ntile; ++t) {
    const int kv0 = t*64;
    {   // stage V^T (coalesced read, transposed scalar writes)
      const int kv = tid >> 2;
      const int d0 = (tid & 3) * 16;
      const unsigned short* src = &V[((long)(b*SEQ + kv0 + kv))*D_MODEL + h*HEAD_DIM + d0];
      s16x8 v0 = *(const s16x8*)&src[0];
      s16x8 v1 = *(const s16x8*)&src[8];
      #pragma unroll
      for (int i=0;i<8;i++) Vt[d0+i][kv]   = (unsigned short)v0[i];
      #pragma unroll
      for (int i=0;i<8;i++) Vt[d0+8+i][kv] = (unsigned short)v1[i];
    }
    // QK^T : K fragments straight from global (L2-resident)
    f32x4 s[4];
    #pragma unroll
    for (int j=0;j<4;j++) {
      const long rowK = (long)(b*SEQ + kv0 + j*16 + lr);
      s16x8 kf0 = *(const s16x8*)&K[rowK*D_MODEL + h*HEAD_DIM + lg*8];
      s16x8 kf1 = *(const s16x8*)&K[rowK*D_MODEL + h*HEAD_DIM + 32 + lg*8];
      f32x4 acc = {};
      acc = __builtin_amdgcn_mfma_f32_16x16x32_bf16(qf0, kf0, acc, 0,0,0);
      acc = __builtin_amdgcn_mfma_f32_16x16x32_bf16(qf1, kf1, acc, 0,0,0);
      s[j] = acc * 0.125f;   // 1/sqrt(64)
    }
    if (t == (int)blockIdx.x) {            // diagonal tile: causal mask
      #pragma unroll
      for (int j=0;j<4;j++)
        #pragma unroll
        for (int r=0;r<4;r++) {
          int kvg = kv0 + j*16 + lr;
          int qg  = q0 + w*16 + lg*4 + r;
          if (kvg > qg) s[j][r] = -1e30f;
        }
    }
    // online softmax (rows live in 16-lane groups)
    float al[4];
    #pragma unroll
    for (int r=0;r<4;r++) {
      float v = fmaxf(fmaxf(s[0][r], s[1][r]), fmaxf(s[2][r], s[3][r]));
      #pragma unroll
      for (int off=1; off<16; off<<=1) v = fmaxf(v, __shfl_xor(v, off, 64));
      float mn = fmaxf(mi[r], v);
      al[r] = __expf(mi[r] - mn);
      mi[r] = mn;
    }
    #pragma unroll
    for (int j=0;j<4;j++)
      #pragma unroll
      for (int r=0;r<4;r++) s[j][r] = __expf(s[j][r] - mi[r]);
    #pragma unroll
    for (int r=0;r<4;r++) {
      float v = s[0][r]+s[1][r]+s[2][r]+s[3][r];
      #pragma unroll
      for (int off=1; off<16; off<<=1) v += __shfl_xor(v, off, 64);
      li[r] = li[r]*al[r] + v;
    }
    #pragma unroll
    for (int d=0;d<4;d++)
      #pragma unroll
      for (int r=0;r<4;r++) oa[d][r] *= al[r];
    #pragma unroll
    for (int j=0;j<4;j++)
      #pragma unroll
      for (int r=0;r<4;r++)
        P[w][lg*4+r][j*16+lr] = f2bf(s[j][r]);
    __syncthreads();                        // Vt + P visible
    // PV
    #pragma unroll
    for (int kk=0;kk<2;kk++) {
      s16x8 pa = *(const s16x8*)&P[w][lr][kk*32+lg*8];
      #pragma unroll
      for (int d=0;d<4;d++) {
        s16x8 vb = *(const s16x8*)&Vt[d*16+lr][kk*32+lg*8];
        oa[d] = __builtin_amdgcn_mfma_f32_16x16x32_bf16(pa, vb, oa[d], 0,0,0);
      }
    }
    __syncthreads();                        // PV done before next Vt overwrite
  }
  #pragma unroll
  for (int d=0;d<4;d++)
    #pragma unroll
    for (int r=0;r<4;r++) {
      long row = (long)(b*SEQ + q0 + w*16 + lg*4 + r);
      O[row*D_MODEL + h*HEAD_DIM + d*16 + lr] = f2bf(oa[d][r] / li[r]);
    }
}

// ---------------- SwiGLU: a = silu(a) * g (bf16, in-place on a) ----------------
__global__ __launch_bounds__(256) void swiglu_k(unsigned short* __restrict__ a,
                                                const unsigned short* __restrict__ g) {
  long i = ((long)blockIdx.x*256 + threadIdx.x)*8;
  s16x8 av = *(const s16x8*)&a[i];
  s16x8 gv = *(const s16x8*)&g[i];
  s16x8 o;
  #pragma unroll
  for (int c=0;c<8;c++) {
    float xx = bf2f((unsigned short)av[c]);
    float yy = bf2f((unsigned short)gv[c]);
    float sg = 1.0f / (1.0f + __expf(-xx));
    o[c] = (short)f2bf(xx * sg * yy);
  }
  *(s16x8*)&a[i] = o;
}

extern "C" void kernel_launch(void* const* d_in, const int* in_sizes, int n_in,
                              void* d_out, int out_size, void* d_ws, size_t ws_size,
                              hipStream_t stream) {
  (void)in_sizes; (void)n_in; (void)out_size; (void)ws_size;
  const float* x    = (const float*)d_in[0];
  const int*   tpos = (const int*)d_in[1];
  const float* ln1  = (const float*)d_in[2];
  const float* qw   = (const float*)d_in[3];
  const float* kw   = (const float*)d_in[4];
  const float* vw   = (const float*)d_in[5];
  const float* ow   = (const float*)d_in[6];
  const float* ln2  = (const float*)d_in[7];
  const float* w1   = (const float*)d_in[8];
  const float* w2   = (const float*)d_in[9];
  const float* w3   = (const float*)d_in[10];
  float* out = (float*)d_out;

  char* ws = (char*)d_ws;
  size_t off = 0;
  auto nalloc = [&](size_t b) { void* p = ws + off; off += (b + 255) & ~(size_t)255; return p; };

  unsigned short* wqb = (unsigned short*)nalloc((size_t)D_MODEL*D_MODEL*2);
  unsigned short* wkb = (unsigned short*)nalloc((size_t)D_MODEL*D_MODEL*2);
  unsigned short* wvb = (unsigned short*)nalloc((size_t)D_MODEL*D_MODEL*2);
  unsigned short* wob = (unsigned short*)nalloc((size_t)D_MODEL*D_MODEL*2);
  unsigned short* w1b = (unsigned short*)nalloc((size_t)D_FF*D_MODEL*2);
  unsigned short* w3b = (unsigned short*)nalloc((size_t)D_FF*D_MODEL*2);
  unsigned short* w2b = (unsigned short*)nalloc((size_t)D_MODEL*D_FF*2);
  float* cosT = (float*)nalloc((size_t)SEQ*32*4);
  float* sinT = (float*)nalloc((size_t)SEQ*32*4);
  unsigned short* h    = (unsigned short*)nalloc((size_t)NTOK*D_MODEL*2);
  unsigned short* qb   = (unsigned short*)nalloc((size_t)NTOK*D_MODEL*2);
  unsigned short* kb   = (unsigned short*)nalloc((size_t)NTOK*D_MODEL*2);
  unsigned short* vb   = (unsigned short*)nalloc((size_t)NTOK*D_MODEL*2);
  unsigned short* ctxb = (unsigned short*)nalloc((size_t)NTOK*D_MODEL*2);
  float* x2 = (float*)nalloc((size_t)NTOK*D_MODEL*4);
  unsigned short* gbuf = (unsigned short*)nalloc((size_t)NTOK*D_FF*2);
  unsigned short* abuf = qb;   // reuse qb..ctxb (exactly NTOK*D_FF bf16) after attention

  cvt_k<<<1024,256,0,stream>>>(qw, wqb, D_MODEL*D_MODEL);
  cvt_k<<<1024,256,0,stream>>>(kw, wkb, D_MODEL*D_MODEL);
  cvt_k<<<1024,256,0,stream>>>(vw, wvb, D_MODEL*D_MODEL);
  cvt_k<<<1024,256,0,stream>>>(ow, wob, D_MODEL*D_MODEL);
  cvt_k<<<2048,256,0,stream>>>(w1, w1b, D_FF*D_MODEL);
  cvt_k<<<2048,256,0,stream>>>(w2, w2b, D_MODEL*D_FF);
  cvt_k<<<2048,256,0,stream>>>(w3, w3b, D_FF*D_MODEL);
  rope_tables_k<<<SEQ*32/256,256,0,stream>>>(tpos, cosT, sinT);

  rmsnorm_k<<<NTOK,256,0,stream>>>(x, ln1, h);
  gemm_bt<0><<<dim3(8,64),256,0,stream>>>(h, wqb, qb, nullptr, nullptr, NTOK, D_MODEL, D_MODEL);
  gemm_bt<0><<<dim3(8,64),256,0,stream>>>(h, wkb, kb, nullptr, nullptr, NTOK, D_MODEL, D_MODEL);
  gemm_bt<0><<<dim3(8,64),256,0,stream>>>(h, wvb, vb, nullptr, nullptr, NTOK, D_MODEL, D_MODEL);
  rope_k<<<4096,256,0,stream>>>(qb, kb, cosT, sinT);
  attn_k<<<dim3(SEQ/64, BATCH*N_HEADS),256,0,stream>>>(qb, kb, vb, ctxb);
  gemm_bt<1><<<dim3(8,64),256,0,stream>>>(ctxb, wob, nullptr, x2, x, NTOK, D_MODEL, D_MODEL);

  rmsnorm_k<<<NTOK,256,0,stream>>>(x2, ln2, h);
  gemm_bt<0><<<dim3(32,64),256,0,stream>>>(h, w1b, abuf, nullptr, nullptr, NTOK, D_FF, D_MODEL);
  gemm_bt<0><<<dim3(32,64),256,0,stream>>>(h, w3b, gbuf, nullptr, nullptr, NTOK, D_FF, D_MODEL);
  swiglu_k<<<(long)NTOK*D_FF/8/256,256,0,stream>>>(abuf, gbuf);
  gemm_bt<1><<<dim3(8,64),256,0,stream>>>(abuf, w2b, nullptr, out, x2, NTOK, D_MODEL, D_FF);
}

// Round 2
// 719.180 us; speedup vs baseline: 1.1702x; 1.1702x over previous
//
#include <hip/hip_runtime.h>
#include <hip/hip_bf16.h>

#define D_MODEL 1024
#define N_HEADS 16
#define HEAD_DIM 64
#define D_FF 4096
#define SEQ 2048
#define BATCH 4
#define NTOK (BATCH*SEQ)

typedef __attribute__((ext_vector_type(4))) float  f32x4;
typedef __attribute__((ext_vector_type(8))) short  s16x8;
typedef __attribute__((ext_vector_type(4))) unsigned short u16x4;

typedef __attribute__((address_space(1))) const unsigned int gas_u32;
typedef __attribute__((address_space(3))) unsigned int las_u32;

__device__ __forceinline__ void gload_lds16(const void* g, void* l) {
  __builtin_amdgcn_global_load_lds((gas_u32*)g, (las_u32*)l, 16, 0, 0);
}

__device__ __forceinline__ float bf2f(unsigned short u) {
  union { unsigned int i; float f; } v; v.i = ((unsigned int)u) << 16; return v.f;
}
__device__ __forceinline__ unsigned short f2bf(float f) {
  union { float f; unsigned int i; } v; v.f = f;
  return (unsigned short)((v.i + 0x7fffu + ((v.i >> 16) & 1u)) >> 16);
}

// ---------------- fp32 -> bf16 convert ----------------
__global__ __launch_bounds__(256) void cvt_k(const float* __restrict__ in,
                                             unsigned short* __restrict__ out, int n) {
  for (long i = ((long)blockIdx.x*256 + threadIdx.x)*4; i < n; i += (long)gridDim.x*1024) {
    f32x4 v = *(const f32x4*)&in[i];
    u16x4 o;
    #pragma unroll
    for (int c=0;c<4;c++) o[c] = f2bf(v[c]);
    *(u16x4*)&out[i] = o;
  }
}

// ---------------- RoPE cos/sin tables: [SEQ][32] ----------------
__global__ __launch_bounds__(256) void rope_tables_k(const int* __restrict__ pos,
                                                     float* __restrict__ cosT,
                                                     float* __restrict__ sinT) {
  int idx = blockIdx.x*256 + threadIdx.x;      // SEQ*32 exact
  int t = idx >> 5, i = idx & 31;
  float p  = (float)pos[t];
  float fr = powf(10000.0f, -(float)i * (1.0f/32.0f));
  float ang = p * fr;
  cosT[idx] = cosf(ang);
  sinT[idx] = sinf(ang);
}

// ---------------- RMSNorm: fp32 in -> bf16 out ----------------
__global__ __launch_bounds__(256) void rmsnorm_k(const float* __restrict__ x,
                                                 const float* __restrict__ wgt,
                                                 unsigned short* __restrict__ out) {
  const long row = blockIdx.x;
  const int t = threadIdx.x;
  f32x4 v = *(const f32x4*)&x[row*D_MODEL + t*4];
  float ss = v[0]*v[0] + v[1]*v[1] + v[2]*v[2] + v[3]*v[3];
  #pragma unroll
  for (int off=1; off<64; off<<=1) ss += __shfl_xor(ss, off, 64);
  __shared__ float red[4];
  if ((t & 63) == 0) red[t >> 6] = ss;
  __syncthreads();
  float tot = red[0] + red[1] + red[2] + red[3];
  float inv = rsqrtf(tot * (1.0f/D_MODEL) + 1e-5f);
  f32x4 wv = *(const f32x4*)&wgt[t*4];
  u16x4 o;
  #pragma unroll
  for (int c=0;c<4;c++) o[c] = f2bf(v[c] * inv * wv[c]);
  *(u16x4*)&out[row*D_MODEL + t*4] = o;
}

// ---------------- RoPE in-place on bf16 q,k ----------------
__global__ __launch_bounds__(256) void rope_k(unsigned short* __restrict__ q,
                                              unsigned short* __restrict__ k,
                                              const float* __restrict__ cosT,
                                              const float* __restrict__ sinT) {
  long idx = (long)blockIdx.x*256 + threadIdx.x;   // NTOK*16*8 exact
  int ig = (int)(idx & 7);
  long th = idx >> 3;
  int h = (int)(th & 15);
  long bt = th >> 4;
  int t = (int)(bt & (SEQ-1));
  long off = bt*D_MODEL + h*HEAD_DIM + ig*8;
  f32x4 cs = *(const f32x4*)&cosT[t*32 + ig*4];
  f32x4 sn = *(const f32x4*)&sinT[t*32 + ig*4];
  s16x8 qv = *(const s16x8*)&q[off];
  s16x8 kv = *(const s16x8*)&k[off];
  s16x8 qo, ko;
  #pragma unroll
  for (int p=0;p<4;p++) {
    float q1 = bf2f((unsigned short)qv[2*p]), q2 = bf2f((unsigned short)qv[2*p+1]);
    qo[2*p]   = (short)f2bf(q1*cs[p] - q2*sn[p]);
    qo[2*p+1] = (short)f2bf(q1*sn[p] + q2*cs[p]);
    float k1 = bf2f((unsigned short)kv[2*p]), k2 = bf2f((unsigned short)kv[2*p+1]);
    ko[2*p]   = (short)f2bf(k1*cs[p] - k2*sn[p]);
    ko[2*p+1] = (short)f2bf(k1*sn[p] + k2*cs[p]);
  }
  *(s16x8*)&q[off] = qo;
  *(s16x8*)&k[off] = ko;
}

// ---------------- GEMM: C[M,N] = A[M,K](bf16) * W[N,K]^T(bf16) ----------------
template<int EPI>
__global__ __launch_bounds__(256) void gemm_bt(const unsigned short* __restrict__ A,
                                               const unsigned short* __restrict__ W,
                                               unsigned short* __restrict__ Cb,
                                               float* __restrict__ Cf,
                                               const float* __restrict__ resid,
                                               int M, int N, int K) {
  __shared__ __align__(16) unsigned short As[128*64];
  __shared__ __align__(16) unsigned short Bs[128*64];

  const int nwg = gridDim.x * gridDim.y;
  int orig = blockIdx.y * gridDim.x + blockIdx.x;
  int swz = orig;
  if ((nwg & 7) == 0) {
    int cpx = nwg >> 3;
    swz = (orig & 7) * cpx + (orig >> 3);
  }
  const int bx = swz % gridDim.x;
  const int by = swz / gridDim.x;

  const int tid = threadIdx.x;
  const int w  = tid >> 6;
  const int l  = tid & 63;
  const int lr = l & 15;
  const int lg = l >> 4;
  const int wm = (w >> 1) * 64;
  const int wn = (w & 1) * 64;

  const long rowA0 = (long)by * 128;
  const long rowB0 = (long)bx * 128;

  f32x4 acc[4][4] = {};

  for (int kt = 0; kt < K; kt += 64) {
    #pragma unroll
    for (int it = 0; it < 4; ++it) {
      int chunk = it*256 + tid;
      int row = chunk >> 3;
      int csw = (chunk & 7) ^ (row & 7);
      gload_lds16(&A[(rowA0 + row)*(long)K + kt + csw*8], &As[chunk*8]);
    }
    #pragma unroll
    for (int it = 0; it < 4; ++it) {
      int chunk = it*256 + tid;
      int row = chunk >> 3;
      int csw = (chunk & 7) ^ (row & 7);
      gload_lds16(&W[(rowB0 + row)*(long)K + kt + csw*8], &Bs[chunk*8]);
    }
    __syncthreads();

    s16x8 af[2][4], bfv[2][4];
    #pragma unroll
    for (int m=0;m<4;m++) {
      int row = wm + m*16 + lr;
      #pragma unroll
      for (int kk=0;kk<2;kk++) {
        int sw = (kk*4+lg) ^ (row & 7);
        af[kk][m] = *(const s16x8*)&As[row*64 + sw*8];
      }
    }
    #pragma unroll
    for (int n=0;n<4;n++) {
      int row = wn + n*16 + lr;
      #pragma unroll
      for (int kk=0;kk<2;kk++) {
        int sw = (kk*4+lg) ^ (row & 7);
        bfv[kk][n] = *(const s16x8*)&Bs[row*64 + sw*8];
      }
    }
    #pragma unroll
    for (int kk=0;kk<2;kk++)
      #pragma unroll
      for (int m=0;m<4;m++)
        #pragma unroll
        for (int n=0;n<4;n++)
          acc[m][n] = __builtin_amdgcn_mfma_f32_16x16x32_bf16(af[kk][m], bfv[kk][n], acc[m][n], 0,0,0);
    __syncthreads();
  }

  #pragma unroll
  for (int m=0;m<4;m++)
    #pragma unroll
    for (int n=0;n<4;n++)
      #pragma unroll
      for (int r=0;r<4;r++) {
        long row = rowA0 + wm + m*16 + lg*4 + r;
        long col = rowB0 + wn + n*16 + lr;
        float val = acc[m][n][r];
        if constexpr (EPI == 0) {
          Cb[row*(long)N + col] = f2bf(val);
        } else {
          Cf[row*(long)N + col] = resid[row*(long)N + col] + val;
        }
      }
}

// ---------------- Flash attention (causal) ----------------
// grid (64 bh, 16 i); block 256 (4 waves x 16 q-rows). Each block does q-tiles
// {i, 31-i} (constant work -> balanced); linear blockIdx % 8 == bh % 8 -> all
// blocks of one head share an XCD L2 (K+V slice 512KB x 8 heads = 4MB = L2).
// V^T double-buffered in LDS with XOR swizzle key (row&7)^((row>>3)&7):
// scalar transpose-writes land in 32 distinct banks (was 4-way), b128 reads
// match the m97-measured-good pattern. One barrier per kv-tile; V global loads
// issued before QK, LDS-written after softmax (async-STAGE split).
__global__ __launch_bounds__(256) void attn_k(const unsigned short* __restrict__ Q,
                                              const unsigned short* __restrict__ K,
                                              const unsigned short* __restrict__ V,
                                              unsigned short* __restrict__ O) {
  const int bh = blockIdx.x;
  const int b = bh >> 4;
  const int h = bh & 15;
  const int tid = threadIdx.x;
  const int w  = tid >> 6;
  const int l  = tid & 63;
  const int lr = l & 15;
  const int lg = l >> 4;

  __shared__ __align__(16) unsigned short Vs[2][64*64];   // swizzled V^T
  __shared__ __align__(16) unsigned short Ps[4][16][72];  // per-wave P

  const int skv = tid >> 2;              // staging: this thread's kv row
  const int sd0 = (tid & 3) * 16;        // and d-range [sd0, sd0+16)
  const long vbase = (long)(b*SEQ)*D_MODEL + h*HEAD_DIM;

  for (int pass = 0; pass < 2; ++pass) {
    const int qt = pass ? 31 - blockIdx.y : blockIdx.y;
    const int q0 = qt * 64;
    const int ntile = qt + 1;

    const long rowQ = (long)(b*SEQ + q0 + w*16 + lr);
    s16x8 qf0 = *(const s16x8*)&Q[rowQ*D_MODEL + h*HEAD_DIM + lg*8];
    s16x8 qf1 = *(const s16x8*)&Q[rowQ*D_MODEL + h*HEAD_DIM + 32 + lg*8];

    float mi[4], li[4];
    f32x4 oa[4] = {};
    #pragma unroll
    for (int r=0;r<4;r++) { mi[r] = -1e30f; li[r] = 0.f; }

    // prologue: stage V tile 0 into buf 0
    {
      const unsigned short* src = &V[vbase + (long)skv*D_MODEL + sd0];
      s16x8 v0 = *(const s16x8*)&src[0];
      s16x8 v1 = *(const s16x8*)&src[8];
      #pragma unroll
      for (int i=0;i<16;i++) {
        int d = sd0 + i;
        int key = (d&7) ^ ((d>>3)&7);
        int c = (skv>>3) ^ key;
        Vs[0][d*64 + c*8 + (skv&7)] = (unsigned short)(i<8 ? v0[i] : v1[i-8]);
      }
    }
    __syncthreads();

    for (int t=0; t<ntile; ++t) {
      const int kv0 = t*64;
      const int cur = t & 1;
      const int nb  = cur ^ 1;
      const bool more = (t+1 < ntile);

      // issue next V tile's global loads early (latency hides under QK)
      s16x8 v0, v1;
      if (more) {
        const unsigned short* src = &V[vbase + (long)((t+1)*64 + skv)*D_MODEL + sd0];
        v0 = *(const s16x8*)&src[0];
        v1 = *(const s16x8*)&src[8];
      }

      // QK^T : K fragments straight from global (L2-resident)
      f32x4 s[4];
      #pragma unroll
      for (int j=0;j<4;j++) {
        const long rowK = (long)(b*SEQ + kv0 + j*16 + lr);
        s16x8 kf0 = *(const s16x8*)&K[rowK*D_MODEL + h*HEAD_DIM + lg*8];
        s16x8 kf1 = *(const s16x8*)&K[rowK*D_MODEL + h*HEAD_DIM + 32 + lg*8];
        f32x4 acc = {};
        acc = __builtin_amdgcn_mfma_f32_16x16x32_bf16(qf0, kf0, acc, 0,0,0);
        acc = __builtin_amdgcn_mfma_f32_16x16x32_bf16(qf1, kf1, acc, 0,0,0);
        s[j] = acc * 0.125f;   // 1/sqrt(64)
      }
      if (t == ntile-1) {               // diagonal tile: causal mask
        #pragma unroll
        for (int j=0;j<4;j++)
          #pragma unroll
          for (int r=0;r<4;r++) {
            int kvg = kv0 + j*16 + lr;
            int qg  = q0 + w*16 + lg*4 + r;
            if (kvg > qg) s[j][r] = -1e30f;
          }
      }
      // online softmax (q-rows live across 16-lane groups)
      float al[4];
      #pragma unroll
      for (int r=0;r<4;r++) {
        float v = fmaxf(fmaxf(s[0][r], s[1][r]), fmaxf(s[2][r], s[3][r]));
        #pragma unroll
        for (int off=1; off<16; off<<=1) v = fmaxf(v, __shfl_xor(v, off, 64));
        float mn = fmaxf(mi[r], v);
        al[r] = __expf(mi[r] - mn);
        mi[r] = mn;
      }
      #pragma unroll
      for (int j=0;j<4;j++)
        #pragma unroll
        for (int r=0;r<4;r++) s[j][r] = __expf(s[j][r] - mi[r]);
      #pragma unroll
      for (int r=0;r<4;r++) {
        float v = s[0][r]+s[1][r]+s[2][r]+s[3][r];
        #pragma unroll
        for (int off=1; off<16; off<<=1) v += __shfl_xor(v, off, 64);
        li[r] = li[r]*al[r] + v;
      }
      #pragma unroll
      for (int d=0;d<4;d++)
        #pragma unroll
        for (int r=0;r<4;r++) oa[d][r] *= al[r];
      // P -> per-wave LDS (no barrier needed: intra-wave DS ops are in-order)
      #pragma unroll
      for (int j=0;j<4;j++)
        #pragma unroll
        for (int r=0;r<4;r++)
          Ps[w][lg*4+r][j*16+lr] = f2bf(s[j][r]);

      // late LDS-write of the prefetched V tile (write side of async-STAGE)
      if (more) {
        #pragma unroll
        for (int i=0;i<16;i++) {
          int d = sd0 + i;
          int key = (d&7) ^ ((d>>3)&7);
          int c = (skv>>3) ^ key;
          Vs[nb][d*64 + c*8 + (skv&7)] = (unsigned short)(i<8 ? v0[i] : v1[i-8]);
        }
      }

      // PV from Vs[cur]
      #pragma unroll
      for (int kk=0;kk<2;kk++) {
        s16x8 pa = *(const s16x8*)&Ps[w][lr][kk*32+lg*8];
        #pragma unroll
        for (int d=0;d<4;d++) {
          int row = d*16 + lr;
          int key = (row&7) ^ ((row>>3)&7);
          int c = (kk*4+lg) ^ key;
          s16x8 vb = *(const s16x8*)&Vs[cur][row*64 + c*8];
          oa[d] = __builtin_amdgcn_mfma_f32_16x16x32_bf16(pa, vb, oa[d], 0,0,0);
        }
      }
      __syncthreads();   // next-tile V ready; cur safe to overwrite at t+2
    }

    #pragma unroll
    for (int d=0;d<4;d++)
      #pragma unroll
      for (int r=0;r<4;r++) {
        long row = (long)(b*SEQ + q0 + w*16 + lg*4 + r);
        O[row*D_MODEL + h*HEAD_DIM + d*16 + lr] = f2bf(oa[d][r] / li[r]);
      }
  }
}

// ---------------- SwiGLU ----------------
__global__ __launch_bounds__(256) void swiglu_k(unsigned short* __restrict__ a,
                                                const unsigned short* __restrict__ g) {
  long i = ((long)blockIdx.x*256 + threadIdx.x)*8;
  s16x8 av = *(const s16x8*)&a[i];
  s16x8 gv = *(const s16x8*)&g[i];
  s16x8 o;
  #pragma unroll
  for (int c=0;c<8;c++) {
    float xx = bf2f((unsigned short)av[c]);
    float yy = bf2f((unsigned short)gv[c]);
    float sg = 1.0f / (1.0f + __expf(-xx));
    o[c] = (short)f2bf(xx * sg * yy);
  }
  *(s16x8*)&a[i] = o;
}

extern "C" void kernel_launch(void* const* d_in, const int* in_sizes, int n_in,
                              void* d_out, int out_size, void* d_ws, size_t ws_size,
                              hipStream_t stream) {
  (void)in_sizes; (void)n_in; (void)out_size; (void)ws_size;
  const float* x    = (const float*)d_in[0];
  const int*   tpos = (const int*)d_in[1];
  const float* ln1  = (const float*)d_in[2];
  const float* qw   = (const float*)d_in[3];
  const float* kw   = (const float*)d_in[4];
  const float* vw   = (const float*)d_in[5];
  const float* ow   = (const float*)d_in[6];
  const float* ln2  = (const float*)d_in[7];
  const float* w1   = (const float*)d_in[8];
  const float* w2   = (const float*)d_in[9];
  const float* w3   = (const float*)d_in[10];
  float* out = (float*)d_out;

  char* ws = (char*)d_ws;
  size_t off = 0;
  auto nalloc = [&](size_t b) { void* p = ws + off; off += (b + 255) & ~(size_t)255; return p; };

  unsigned short* wqb = (unsigned short*)nalloc((size_t)D_MODEL*D_MODEL*2);
  unsigned short* wkb = (unsigned short*)nalloc((size_t)D_MODEL*D_MODEL*2);
  unsigned short* wvb = (unsigned short*)nalloc((size_t)D_MODEL*D_MODEL*2);
  unsigned short* wob = (unsigned short*)nalloc((size_t)D_MODEL*D_MODEL*2);
  unsigned short* w1b = (unsigned short*)nalloc((size_t)D_FF*D_MODEL*2);
  unsigned short* w3b = (unsigned short*)nalloc((size_t)D_FF*D_MODEL*2);
  unsigned short* w2b = (unsigned short*)nalloc((size_t)D_MODEL*D_FF*2);
  float* cosT = (float*)nalloc((size_t)SEQ*32*4);
  float* sinT = (float*)nalloc((size_t)SEQ*32*4);
  unsigned short* h    = (unsigned short*)nalloc((size_t)NTOK*D_MODEL*2);
  unsigned short* qb   = (unsigned short*)nalloc((size_t)NTOK*D_MODEL*2);
  unsigned short* kb   = (unsigned short*)nalloc((size_t)NTOK*D_MODEL*2);
  unsigned short* vb   = (unsigned short*)nalloc((size_t)NTOK*D_MODEL*2);
  unsigned short* ctxb = (unsigned short*)nalloc((size_t)NTOK*D_MODEL*2);
  float* x2 = (float*)nalloc((size_t)NTOK*D_MODEL*4);
  unsigned short* gbuf = (unsigned short*)nalloc((size_t)NTOK*D_FF*2);
  unsigned short* abuf = qb;   // reuse qb..ctxb (exactly NTOK*D_FF bf16) after attention

  cvt_k<<<1024,256,0,stream>>>(qw, wqb, D_MODEL*D_MODEL);
  cvt_k<<<1024,256,0,stream>>>(kw, wkb, D_MODEL*D_MODEL);
  cvt_k<<<1024,256,0,stream>>>(vw, wvb, D_MODEL*D_MODEL);
  cvt_k<<<1024,256,0,stream>>>(ow, wob, D_MODEL*D_MODEL);
  cvt_k<<<2048,256,0,stream>>>(w1, w1b, D_FF*D_MODEL);
  cvt_k<<<2048,256,0,stream>>>(w2, w2b, D_MODEL*D_FF);
  cvt_k<<<2048,256,0,stream>>>(w3, w3b, D_FF*D_MODEL);
  rope_tables_k<<<SEQ*32/256,256,0,stream>>>(tpos, cosT, sinT);

  rmsnorm_k<<<NTOK,256,0,stream>>>(x, ln1, h);
  gemm_bt<0><<<dim3(8,64),256,0,stream>>>(h, wqb, qb, nullptr, nullptr, NTOK, D_MODEL, D_MODEL);
  gemm_bt<0><<<dim3(8,64),256,0,stream>>>(h, wkb, kb, nullptr, nullptr, NTOK, D_MODEL, D_MODEL);
  gemm_bt<0><<<dim3(8,64),256,0,stream>>>(h, wvb, vb, nullptr, nullptr, NTOK, D_MODEL, D_MODEL);
  rope_k<<<4096,256,0,stream>>>(qb, kb, cosT, sinT);
  attn_k<<<dim3(64,16),256,0,stream>>>(qb, kb, vb, ctxb);
  gemm_bt<1><<<dim3(8,64),256,0,stream>>>(ctxb, wob, nullptr, x2, x, NTOK, D_MODEL, D_MODEL);

  rmsnorm_k<<<NTOK,256,0,stream>>>(x2, ln2, h);
  gemm_bt<0><<<dim3(32,64),256,0,stream>>>(h, w1b, abuf, nullptr, nullptr, NTOK, D_FF, D_MODEL);
  gemm_bt<0><<<dim3(32,64),256,0,stream>>>(h, w3b, gbuf, nullptr, nullptr, NTOK, D_FF, D_MODEL);
  swiglu_k<<<(long)NTOK*D_FF/8/256,256,0,stream>>>(abuf, gbuf);
  gemm_bt<1><<<dim3(8,64),256,0,stream>>>(abuf, w2b, nullptr, out, x2, NTOK, D_MODEL, D_FF);
}

// Round 3
// 647.134 us; speedup vs baseline: 1.3004x; 1.1113x over previous
//
#include <hip/hip_runtime.h>
#include <hip/hip_bf16.h>

#define D_MODEL 1024
#define N_HEADS 16
#define HEAD_DIM 64
#define D_FF 4096
#define SEQ 2048
#define BATCH 4
#define NTOK (BATCH*SEQ)
#define QS 3072   // fused qkv row stride

typedef __attribute__((ext_vector_type(4))) float  f32x4;
typedef __attribute__((ext_vector_type(8))) short  s16x8;
typedef __attribute__((ext_vector_type(4))) unsigned short u16x4;

typedef __attribute__((address_space(1))) const unsigned int gas_u32;
typedef __attribute__((address_space(3))) unsigned int las_u32;

__device__ __forceinline__ void gload_lds16(const void* g, void* l) {
  __builtin_amdgcn_global_load_lds((gas_u32*)g, (las_u32*)l, 16, 0, 0);
}

__device__ __forceinline__ float bf2f(unsigned short u) {
  union { unsigned int i; float f; } v; v.i = ((unsigned int)u) << 16; return v.f;
}
__device__ __forceinline__ unsigned short f2bf(float f) {
  union { float f; unsigned int i; } v; v.f = f;
  return (unsigned short)((v.i + 0x7fffu + ((v.i >> 16) & 1u)) >> 16);
}

// ---------------- fp32 -> bf16 convert ----------------
__global__ __launch_bounds__(256) void cvt_k(const float* __restrict__ in,
                                             unsigned short* __restrict__ out, int n) {
  for (long i = ((long)blockIdx.x*256 + threadIdx.x)*4; i < n; i += (long)gridDim.x*1024) {
    f32x4 v = *(const f32x4*)&in[i];
    u16x4 o;
    #pragma unroll
    for (int c=0;c<4;c++) o[c] = f2bf(v[c]);
    *(u16x4*)&out[i] = o;
  }
}

// ---------------- RoPE cos/sin tables: [SEQ][32] ----------------
__global__ __launch_bounds__(256) void rope_tables_k(const int* __restrict__ pos,
                                                     float* __restrict__ cosT,
                                                     float* __restrict__ sinT) {
  int idx = blockIdx.x*256 + threadIdx.x;      // SEQ*32 exact
  int t = idx >> 5, i = idx & 31;
  float p  = (float)pos[t];
  float fr = powf(10000.0f, -(float)i * (1.0f/32.0f));
  float ang = p * fr;
  cosT[idx] = cosf(ang);
  sinT[idx] = sinf(ang);
}

// ---------------- RMSNorm: fp32 in -> bf16 out ----------------
__global__ __launch_bounds__(256) void rmsnorm_k(const float* __restrict__ x,
                                                 const float* __restrict__ wgt,
                                                 unsigned short* __restrict__ out) {
  const long row = blockIdx.x;
  const int t = threadIdx.x;
  f32x4 v = *(const f32x4*)&x[row*D_MODEL + t*4];
  float ss = v[0]*v[0] + v[1]*v[1] + v[2]*v[2] + v[3]*v[3];
  #pragma unroll
  for (int off=1; off<64; off<<=1) ss += __shfl_xor(ss, off, 64);
  __shared__ float red[4];
  if ((t & 63) == 0) red[t >> 6] = ss;
  __syncthreads();
  float tot = red[0] + red[1] + red[2] + red[3];
  float inv = rsqrtf(tot * (1.0f/D_MODEL) + 1e-5f);
  f32x4 wv = *(const f32x4*)&wgt[t*4];
  u16x4 o;
  #pragma unroll
  for (int c=0;c<4;c++) o[c] = f2bf(v[c] * inv * wv[c]);
  *(u16x4*)&out[row*D_MODEL + t*4] = o;
}

// ---------------- RoPE in-place on fused qkv; Q pre-scaled by 1/8 ----------------
__global__ __launch_bounds__(256) void rope_k(unsigned short* __restrict__ qkv,
                                              const float* __restrict__ cosT,
                                              const float* __restrict__ sinT) {
  long idx = (long)blockIdx.x*256 + threadIdx.x;   // NTOK*16*8 exact
  int ig = (int)(idx & 7);
  long th = idx >> 3;
  int h = (int)(th & 15);
  long bt = th >> 4;
  int t = (int)(bt & (SEQ-1));
  long off = bt*QS + h*HEAD_DIM + ig*8;
  f32x4 cs = *(const f32x4*)&cosT[t*32 + ig*4];
  f32x4 sn = *(const f32x4*)&sinT[t*32 + ig*4];
  s16x8 qv = *(const s16x8*)&qkv[off];
  s16x8 kv = *(const s16x8*)&qkv[off + 1024];
  s16x8 qo, ko;
  #pragma unroll
  for (int p=0;p<4;p++) {
    float q1 = bf2f((unsigned short)qv[2*p]), q2 = bf2f((unsigned short)qv[2*p+1]);
    qo[2*p]   = (short)f2bf((q1*cs[p] - q2*sn[p]) * 0.125f);  // fold 1/sqrt(64)
    qo[2*p+1] = (short)f2bf((q1*sn[p] + q2*cs[p]) * 0.125f);
    float k1 = bf2f((unsigned short)kv[2*p]), k2 = bf2f((unsigned short)kv[2*p+1]);
    ko[2*p]   = (short)f2bf(k1*cs[p] - k2*sn[p]);
    ko[2*p+1] = (short)f2bf(k1*sn[p] + k2*cs[p]);
  }
  *(s16x8*)&qkv[off] = qo;
  *(s16x8*)&qkv[off + 1024] = ko;
}

// ---------------- GEMM (m97 2-barrier): C = A * W^T ----------------
template<int EPI>
__global__ __launch_bounds__(256) void gemm_bt(const unsigned short* __restrict__ A,
                                               const unsigned short* __restrict__ W,
                                               unsigned short* __restrict__ Cb,
                                               float* __restrict__ Cf,
                                               const float* __restrict__ resid,
                                               int M, int N, int K) {
  __shared__ __align__(16) unsigned short As[128*64];
  __shared__ __align__(16) unsigned short Bs[128*64];

  const int nwg = gridDim.x * gridDim.y;
  int orig = blockIdx.y * gridDim.x + blockIdx.x;
  int swz = orig;
  if ((nwg & 7) == 0) {
    int cpx = nwg >> 3;
    swz = (orig & 7) * cpx + (orig >> 3);
  }
  const int bx = swz % gridDim.x;
  const int by = swz / gridDim.x;

  const int tid = threadIdx.x;
  const int w  = tid >> 6;
  const int l  = tid & 63;
  const int lr = l & 15;
  const int lg = l >> 4;
  const int wm = (w >> 1) * 64;
  const int wn = (w & 1) * 64;

  const long rowA0 = (long)by * 128;
  const long rowB0 = (long)bx * 128;

  f32x4 acc[4][4] = {};

  for (int kt = 0; kt < K; kt += 64) {
    #pragma unroll
    for (int it = 0; it < 4; ++it) {
      int chunk = it*256 + tid;
      int row = chunk >> 3;
      int csw = (chunk & 7) ^ (row & 7);
      gload_lds16(&A[(rowA0 + row)*(long)K + kt + csw*8], &As[chunk*8]);
    }
    #pragma unroll
    for (int it = 0; it < 4; ++it) {
      int chunk = it*256 + tid;
      int row = chunk >> 3;
      int csw = (chunk & 7) ^ (row & 7);
      gload_lds16(&W[(rowB0 + row)*(long)K + kt + csw*8], &Bs[chunk*8]);
    }
    __syncthreads();

    s16x8 af[2][4], bfv[2][4];
    #pragma unroll
    for (int m=0;m<4;m++) {
      int row = wm + m*16 + lr;
      #pragma unroll
      for (int kk=0;kk<2;kk++) {
        int sw = (kk*4+lg) ^ (row & 7);
        af[kk][m] = *(const s16x8*)&As[row*64 + sw*8];
      }
    }
    #pragma unroll
    for (int n=0;n<4;n++) {
      int row = wn + n*16 + lr;
      #pragma unroll
      for (int kk=0;kk<2;kk++) {
        int sw = (kk*4+lg) ^ (row & 7);
        bfv[kk][n] = *(const s16x8*)&Bs[row*64 + sw*8];
      }
    }
    #pragma unroll
    for (int kk=0;kk<2;kk++)
      #pragma unroll
      for (int m=0;m<4;m++)
        #pragma unroll
        for (int n=0;n<4;n++)
          acc[m][n] = __builtin_amdgcn_mfma_f32_16x16x32_bf16(af[kk][m], bfv[kk][n], acc[m][n], 0,0,0);
    __syncthreads();
  }

  #pragma unroll
  for (int m=0;m<4;m++)
    #pragma unroll
    for (int n=0;n<4;n++)
      #pragma unroll
      for (int r=0;r<4;r++) {
        long row = rowA0 + wm + m*16 + lg*4 + r;
        long col = rowB0 + wn + n*16 + lr;
        float val = acc[m][n][r];
        if constexpr (EPI == 0) {
          Cb[row*(long)N + col] = f2bf(val);
        } else {
          Cf[row*(long)N + col] = resid[row*(long)N + col] + val;
        }
      }
}

// ---------------- GEMM experiment: double-buffered LDS, single barrier/K-step ----------------
// T3-minimum: issue next-tile global_load_lds BEFORE computing current tile;
// one __syncthreads per K-step drains the in-flight loads. 64KB LDS (2 blk/CU).
template<int EPI>
__global__ __launch_bounds__(256) void gemm_db(const unsigned short* __restrict__ A,
                                               const unsigned short* __restrict__ W,
                                               unsigned short* __restrict__ Cb,
                                               float* __restrict__ Cf,
                                               const float* __restrict__ resid,
                                               int M, int N, int K) {
  __shared__ __align__(16) unsigned short As[2][128*64];
  __shared__ __align__(16) unsigned short Bs[2][128*64];

  const int nwg = gridDim.x * gridDim.y;
  int orig = blockIdx.y * gridDim.x + blockIdx.x;
  int swz = orig;
  if ((nwg & 7) == 0) {
    int cpx = nwg >> 3;
    swz = (orig & 7) * cpx + (orig >> 3);
  }
  const int bx = swz % gridDim.x;
  const int by = swz / gridDim.x;

  const int tid = threadIdx.x;
  const int w  = tid >> 6;
  const int l  = tid & 63;
  const int lr = l & 15;
  const int lg = l >> 4;
  const int wm = (w >> 1) * 64;
  const int wn = (w & 1) * 64;

  const long rowA0 = (long)by * 128;
  const long rowB0 = (long)bx * 128;

  f32x4 acc[4][4] = {};
  const int nk = K >> 6;

  #pragma unroll
  for (int it = 0; it < 4; ++it) {   // prologue: stage k-tile 0 -> buf 0
    int chunk = it*256 + tid;
    int row = chunk >> 3;
    int csw = (chunk & 7) ^ (row & 7);
    gload_lds16(&A[(rowA0 + row)*(long)K + csw*8], &As[0][chunk*8]);
    gload_lds16(&W[(rowB0 + row)*(long)K + csw*8], &Bs[0][chunk*8]);
  }
  __syncthreads();

  int cur = 0;
  for (int ki = 0; ki < nk; ++ki) {
    if (ki + 1 < nk) {               // issue next tile loads before compute
      int kt = (ki + 1) << 6;
      #pragma unroll
      for (int it = 0; it < 4; ++it) {
        int chunk = it*256 + tid;
        int row = chunk >> 3;
        int csw = (chunk & 7) ^ (row & 7);
        gload_lds16(&A[(rowA0 + row)*(long)K + kt + csw*8], &As[cur^1][chunk*8]);
        gload_lds16(&W[(rowB0 + row)*(long)K + kt + csw*8], &Bs[cur^1][chunk*8]);
      }
    }
    s16x8 af[2][4], bfv[2][4];
    #pragma unroll
    for (int m=0;m<4;m++) {
      int row = wm + m*16 + lr;
      #pragma unroll
      for (int kk=0;kk<2;kk++) {
        int sw = (kk*4+lg) ^ (row & 7);
        af[kk][m] = *(const s16x8*)&As[cur][row*64 + sw*8];
      }
    }
    #pragma unroll
    for (int n=0;n<4;n++) {
      int row = wn + n*16 + lr;
      #pragma unroll
      for (int kk=0;kk<2;kk++) {
        int sw = (kk*4+lg) ^ (row & 7);
        bfv[kk][n] = *(const s16x8*)&Bs[cur][row*64 + sw*8];
      }
    }
    #pragma unroll
    for (int kk=0;kk<2;kk++)
      #pragma unroll
      for (int m=0;m<4;m++)
        #pragma unroll
        for (int n=0;n<4;n++)
          acc[m][n] = __builtin_amdgcn_mfma_f32_16x16x32_bf16(af[kk][m], bfv[kk][n], acc[m][n], 0,0,0);
    __syncthreads();                 // single barrier: reads done + next tile landed
    cur ^= 1;
  }

  #pragma unroll
  for (int m=0;m<4;m++)
    #pragma unroll
    for (int n=0;n<4;n++)
      #pragma unroll
      for (int r=0;r<4;r++) {
        long row = rowA0 + wm + m*16 + lg*4 + r;
        long col = rowB0 + wn + n*16 + lr;
        float val = acc[m][n][r];
        if constexpr (EPI == 0) {
          Cb[row*(long)N + col] = f2bf(val);
        } else {
          Cf[row*(long)N + col] = resid[row*(long)N + col] + val;
        }
      }
}

// ---------------- Flash attention (causal), swapped QK^T, K via global_load_lds ----------------
// Swapped mfma(K,Q) -> D[k][q]: per-q reductions are 15 in-lane ops + 2 shfl.
// alpha/l redistributed via ds_bpermute. K double-buffered in LDS (async DMA,
// inverse-source-swizzle). V double-buffered (reg-staged transpose, swizzled).
// P^T via chunk-XOR stride-64 LDS. Total LDS exactly 40KB -> 4 blocks/CU.
__global__ __launch_bounds__(256) void attn_k(const unsigned short* __restrict__ QKV,
                                              unsigned short* __restrict__ O) {
  const int bh = blockIdx.x;
  const int b = bh >> 4;
  const int h = bh & 15;
  const int tid = threadIdx.x;
  const int w  = tid >> 6;
  const int l  = tid & 63;
  const int lr = l & 15;
  const int lg = l >> 4;

  const unsigned short* Qp = QKV;
  const unsigned short* Kp = QKV + 1024;
  const unsigned short* Vp = QKV + 2048;

  __shared__ __align__(16) unsigned short Ks[2][64*64];   // 16KB
  __shared__ __align__(16) unsigned short Vs[2][64*64];   // 16KB
  __shared__ __align__(16) unsigned short Ps[4][16][64];  // 8KB

  const int skv = tid >> 2;              // V staging: kv row
  const int sd0 = (tid & 3) * 16;        // and d-range
  const long hbase = (long)(b*SEQ)*QS + h*HEAD_DIM;

  for (int pass = 0; pass < 2; ++pass) {
    const int qt = pass ? 31 - (int)blockIdx.y : (int)blockIdx.y;
    const int q0 = qt * 64;
    const int ntile = qt + 1;

    const long rowQ = (long)(b*SEQ + q0 + w*16 + lr);
    s16x8 qf0 = *(const s16x8*)&Qp[rowQ*QS + h*HEAD_DIM + lg*8];
    s16x8 qf1 = *(const s16x8*)&Qp[rowQ*QS + h*HEAD_DIM + 32 + lg*8];

    float mi = -1e30f, li = 0.f;
    f32x4 oa[4] = {};

    // prologue: stage K,V tile 0 -> buf 0
    #pragma unroll
    for (int it=0; it<2; ++it) {
      int chunk = it*256 + tid;
      int row = chunk >> 3;
      int csw = (chunk & 7) ^ (row & 7);
      gload_lds16(&Kp[hbase + (long)row*QS + csw*8], &Ks[0][chunk*8]);
    }
    {
      const unsigned short* src = &Vp[hbase + (long)skv*QS + sd0];
      s16x8 v0 = *(const s16x8*)&src[0];
      s16x8 v1 = *(const s16x8*)&src[8];
      #pragma unroll
      for (int i=0;i<16;i++) {
        int d = sd0 + i;
        int key = (d&7) ^ ((d>>3)&7);
        int c = (skv>>3) ^ key;
        Vs[0][d*64 + c*8 + (skv&7)] = (unsigned short)(i<8 ? v0[i] : v1[i-8]);
      }
    }
    __syncthreads();

    for (int t=0; t<ntile; ++t) {
      const int kv0 = t*64;
      const int cur = t & 1;
      const int nb  = cur ^ 1;
      const bool more = (t+1 < ntile);

      // async prefetch of next K tile + reg-load of next V tile
      s16x8 v0, v1;
      if (more) {
        #pragma unroll
        for (int it=0; it<2; ++it) {
          int chunk = it*256 + tid;
          int row = chunk >> 3;
          int csw = (chunk & 7) ^ (row & 7);
          gload_lds16(&Kp[hbase + (long)(kv0 + 64 + row)*QS + csw*8], &Ks[nb][chunk*8]);
        }
        const unsigned short* src = &Vp[hbase + (long)(kv0 + 64 + skv)*QS + sd0];
        v0 = *(const s16x8*)&src[0];
        v1 = *(const s16x8*)&src[8];
      }

      // QK^T swapped: D[k][q], k = kv0+j*16+lg*4+r, q = q0+w*16+lr
      f32x4 s[4];
      __builtin_amdgcn_s_setprio(1);
      #pragma unroll
      for (int j=0;j<4;j++) {
        int krow = j*16 + lr;
        s16x8 kf0 = *(const s16x8*)&Ks[cur][krow*64 + ((lg)     ^ (krow&7))*8];
        s16x8 kf1 = *(const s16x8*)&Ks[cur][krow*64 + ((4 + lg) ^ (krow&7))*8];
        f32x4 acc = {};
        acc = __builtin_amdgcn_mfma_f32_16x16x32_bf16(kf0, qf0, acc, 0,0,0);
        acc = __builtin_amdgcn_mfma_f32_16x16x32_bf16(kf1, qf1, acc, 0,0,0);
        s[j] = acc;
      }
      __builtin_amdgcn_s_setprio(0);

      if (t == ntile-1) {               // diagonal: causal mask
        #pragma unroll
        for (int j=0;j<4;j++)
          #pragma unroll
          for (int r=0;r<4;r++)
            if (kv0 + j*16 + lg*4 + r > q0 + w*16 + lr) s[j][r] = -1e30f;
      }

      // online softmax: q per-lane (q = lr), k in-register
      float pmax = s[0][0];
      #pragma unroll
      for (int j=0;j<4;j++)
        #pragma unroll
        for (int r=0;r<4;r++) pmax = fmaxf(pmax, s[j][r]);
      pmax = fmaxf(pmax, __shfl_xor(pmax, 16, 64));
      pmax = fmaxf(pmax, __shfl_xor(pmax, 32, 64));
      float mn = fmaxf(mi, pmax);
      float al = __expf(mi - mn);
      mi = mn;
      float psum = 0.f;
      #pragma unroll
      for (int j=0;j<4;j++)
        #pragma unroll
        for (int r=0;r<4;r++) {
          float p = __expf(s[j][r] - mn);
          s[j][r] = p;
          psum += p;
        }
      psum += __shfl_xor(psum, 16, 64);
      psum += __shfl_xor(psum, 32, 64);
      li = li*al + psum;

      // alpha for this lane's O rows (q = lg*4+r) via bpermute
      float alq[4];
      #pragma unroll
      for (int r=0;r<4;r++) alq[r] = __shfl(al, lg*4 + r, 64);
      #pragma unroll
      for (int d=0;d<4;d++)
        #pragma unroll
        for (int r=0;r<4;r++) oa[d][r] *= alq[r];

      // P^T -> LDS (row q=lr, chunk-XOR swizzled cols)
      #pragma unroll
      for (int j=0;j<4;j++)
        #pragma unroll
        for (int r=0;r<4;r++) {
          int k = j*16 + lg*4 + r;
          int pos = ((k>>3) ^ (lr&7))*8 + (k&7);
          Ps[w][lr][pos] = f2bf(s[j][r]);
        }

      // late LDS-write of prefetched V tile
      if (more) {
        #pragma unroll
        for (int i=0;i<16;i++) {
          int d = sd0 + i;
          int key = (d&7) ^ ((d>>3)&7);
          int c = (skv>>3) ^ key;
          Vs[nb][d*64 + c*8 + (skv&7)] = (unsigned short)(i<8 ? v0[i] : v1[i-8]);
        }
      }

      // PV: O[q][dcol], A = P rows (in-order same-wave DS: writes visible)
      __builtin_amdgcn_s_setprio(1);
      #pragma unroll
      for (int kk=0;kk<2;kk++) {
        s16x8 pa = *(const s16x8*)&Ps[w][lr][((kk*4 + lg) ^ (lr&7))*8];
        #pragma unroll
        for (int d=0;d<4;d++) {
          int vrow = d*16 + lr;
          int key = (vrow&7) ^ ((vrow>>3)&7);
          int c = (kk*4 + lg) ^ key;
          s16x8 vb = *(const s16x8*)&Vs[cur][vrow*64 + c*8];
          oa[d] = __builtin_amdgcn_mfma_f32_16x16x32_bf16(pa, vb, oa[d], 0,0,0);
        }
      }
      __builtin_amdgcn_s_setprio(0);
      __syncthreads();   // K DMA landed, all reads of cur done
    }

    float liq[4];
    #pragma unroll
    for (int r=0;r<4;r++) liq[r] = __shfl(li, lg*4 + r, 64);
    #pragma unroll
    for (int d=0;d<4;d++)
      #pragma unroll
      for (int r=0;r<4;r++) {
        long row = (long)(b*SEQ + q0 + w*16 + lg*4 + r);
        O[row*D_MODEL + h*HEAD_DIM + d*16 + lr] = f2bf(oa[d][r] / liq[r]);
      }
  }
}

// ---------------- SwiGLU ----------------
__global__ __launch_bounds__(256) void swiglu_k(unsigned short* __restrict__ a,
                                                const unsigned short* __restrict__ g) {
  long i = ((long)blockIdx.x*256 + threadIdx.x)*8;
  s16x8 av = *(const s16x8*)&a[i];
  s16x8 gv = *(const s16x8*)&g[i];
  s16x8 o;
  #pragma unroll
  for (int c=0;c<8;c++) {
    float xx = bf2f((unsigned short)av[c]);
    float yy = bf2f((unsigned short)gv[c]);
    float sg = 1.0f / (1.0f + __expf(-xx));
    o[c] = (short)f2bf(xx * sg * yy);
  }
  *(s16x8*)&a[i] = o;
}

extern "C" void kernel_launch(void* const* d_in, const int* in_sizes, int n_in,
                              void* d_out, int out_size, void* d_ws, size_t ws_size,
                              hipStream_t stream) {
  (void)in_sizes; (void)n_in; (void)out_size; (void)ws_size;
  const float* x    = (const float*)d_in[0];
  const int*   tpos = (const int*)d_in[1];
  const float* ln1  = (const float*)d_in[2];
  const float* qw   = (const float*)d_in[3];
  const float* kw   = (const float*)d_in[4];
  const float* vw   = (const float*)d_in[5];
  const float* ow   = (const float*)d_in[6];
  const float* ln2  = (const float*)d_in[7];
  const float* w1   = (const float*)d_in[8];
  const float* w2   = (const float*)d_in[9];
  const float* w3   = (const float*)d_in[10];
  float* out = (float*)d_out;

  char* ws = (char*)d_ws;
  size_t off = 0;
  auto nalloc = [&](size_t b) { void* p = ws + off; off += (b + 255) & ~(size_t)255; return p; };

  unsigned short* wqkvb = (unsigned short*)nalloc((size_t)3072*D_MODEL*2);
  unsigned short* wob   = (unsigned short*)nalloc((size_t)D_MODEL*D_MODEL*2);
  unsigned short* w1b   = (unsigned short*)nalloc((size_t)D_FF*D_MODEL*2);
  unsigned short* w3b   = (unsigned short*)nalloc((size_t)D_FF*D_MODEL*2);
  unsigned short* w2b   = (unsigned short*)nalloc((size_t)D_MODEL*D_FF*2);
  float* cosT = (float*)nalloc((size_t)SEQ*32*4);
  float* sinT = (float*)nalloc((size_t)SEQ*32*4);
  unsigned short* hbuf = (unsigned short*)nalloc((size_t)NTOK*D_MODEL*2);
  unsigned short* qkv  = (unsigned short*)nalloc((size_t)NTOK*QS*2);      // 50.33MB
  unsigned short* ctxb = (unsigned short*)nalloc((size_t)NTOK*D_MODEL*2); // 16.78MB, adjacent
  float* x2 = (float*)nalloc((size_t)NTOK*D_MODEL*4);
  unsigned short* gbuf = (unsigned short*)nalloc((size_t)NTOK*D_FF*2);
  unsigned short* abuf = qkv;   // after O-proj, qkv+ctxb region (exactly NTOK*D_FF bf16) is free

  cvt_k<<<1024,256,0,stream>>>(qw, wqkvb,                 D_MODEL*D_MODEL);
  cvt_k<<<1024,256,0,stream>>>(kw, wqkvb + 1024*D_MODEL,  D_MODEL*D_MODEL);
  cvt_k<<<1024,256,0,stream>>>(vw, wqkvb + 2048*D_MODEL,  D_MODEL*D_MODEL);
  cvt_k<<<1024,256,0,stream>>>(ow, wob, D_MODEL*D_MODEL);
  cvt_k<<<2048,256,0,stream>>>(w1, w1b, D_FF*D_MODEL);
  cvt_k<<<2048,256,0,stream>>>(w2, w2b, D_MODEL*D_FF);
  cvt_k<<<2048,256,0,stream>>>(w3, w3b, D_FF*D_MODEL);
  rope_tables_k<<<SEQ*32/256,256,0,stream>>>(tpos, cosT, sinT);

  rmsnorm_k<<<NTOK,256,0,stream>>>(x, ln1, hbuf);
  gemm_bt<0><<<dim3(24,64),256,0,stream>>>(hbuf, wqkvb, qkv, nullptr, nullptr, NTOK, QS, D_MODEL);
  rope_k<<<4096,256,0,stream>>>(qkv, cosT, sinT);
  attn_k<<<dim3(64,16),256,0,stream>>>(qkv, ctxb);
  gemm_bt<1><<<dim3(8,64),256,0,stream>>>(ctxb, wob, nullptr, x2, x, NTOK, D_MODEL, D_MODEL);

  rmsnorm_k<<<NTOK,256,0,stream>>>(x2, ln2, hbuf);
  gemm_db<0><<<dim3(32,64),256,0,stream>>>(hbuf, w1b, abuf, nullptr, nullptr, NTOK, D_FF, D_MODEL);  // EXPERIMENT: dbuf pipeline
  gemm_bt<0><<<dim3(32,64),256,0,stream>>>(hbuf, w3b, gbuf, nullptr, nullptr, NTOK, D_FF, D_MODEL);  // CONTROL: m97 2-barrier
  swiglu_k<<<(long)NTOK*D_FF/8/256,256,0,stream>>>(abuf, gbuf);
  gemm_bt<1><<<dim3(8,64),256,0,stream>>>(abuf, w2b, nullptr, out, x2, NTOK, D_MODEL, D_FF);
}

// Round 5
// 637.786 us; speedup vs baseline: 1.3195x; 1.0147x over previous
//
#include <hip/hip_runtime.h>
#include <hip/hip_bf16.h>

#define D_MODEL 1024
#define N_HEADS 16
#define HEAD_DIM 64
#define D_FF 4096
#define SEQ 2048
#define BATCH 4
#define NTOK (BATCH*SEQ)
#define QS 3072   // fused qkv row stride

typedef __attribute__((ext_vector_type(4))) float  f32x4;
typedef __attribute__((ext_vector_type(8))) short  s16x8;
typedef __attribute__((ext_vector_type(4))) unsigned short u16x4;

typedef __attribute__((address_space(1))) const unsigned int gas_u32;
typedef __attribute__((address_space(3))) unsigned int las_u32;

__device__ __forceinline__ void gload_lds16(const void* g, void* l) {
  __builtin_amdgcn_global_load_lds((gas_u32*)g, (las_u32*)l, 16, 0, 0);
}

__device__ __forceinline__ float bf2f(unsigned short u) {
  union { unsigned int i; float f; } v; v.i = ((unsigned int)u) << 16; return v.f;
}
__device__ __forceinline__ unsigned short f2bf(float f) {
  union { float f; unsigned int i; } v; v.f = f;
  return (unsigned short)((v.i + 0x7fffu + ((v.i >> 16) & 1u)) >> 16);
}

// ---------------- fused fp32 -> bf16 weight convert (one launch, 16M elems) ----------------
__global__ __launch_bounds__(256) void cvt_all_k(const float* __restrict__ qw, const float* __restrict__ kw,
                                                 const float* __restrict__ vw, const float* __restrict__ ow,
                                                 const float* __restrict__ w1, const float* __restrict__ w2,
                                                 const float* __restrict__ w3,
                                                 unsigned short* __restrict__ wqkv, unsigned short* __restrict__ wo,
                                                 unsigned short* __restrict__ b1, unsigned short* __restrict__ b2,
                                                 unsigned short* __restrict__ b3) {
  const long MM = 1 << 20;
  long e = ((long)blockIdx.x*256 + threadIdx.x)*4;   // 16M elements exact, 16384 blocks
  const float* src; unsigned short* dst; long off;
  if      (e <    MM) { src = qw; dst = wqkv;        off = e; }
  else if (e <  2*MM) { src = kw; dst = wqkv + MM;   off = e - MM; }
  else if (e <  3*MM) { src = vw; dst = wqkv + 2*MM; off = e - 2*MM; }
  else if (e <  4*MM) { src = ow; dst = wo;          off = e - 3*MM; }
  else if (e <  8*MM) { src = w1; dst = b1;          off = e - 4*MM; }
  else if (e < 12*MM) { src = w2; dst = b2;          off = e - 8*MM; }
  else                { src = w3; dst = b3;          off = e - 12*MM; }
  f32x4 v = *(const f32x4*)&src[off];
  u16x4 o;
  #pragma unroll
  for (int c=0;c<4;c++) o[c] = f2bf(v[c]);
  *(u16x4*)&dst[off] = o;
}

// ---------------- RoPE cos/sin tables: [SEQ][32] ----------------
__global__ __launch_bounds__(256) void rope_tables_k(const int* __restrict__ pos,
                                                     float* __restrict__ cosT,
                                                     float* __restrict__ sinT) {
  int idx = blockIdx.x*256 + threadIdx.x;      // SEQ*32 exact
  int t = idx >> 5, i = idx & 31;
  float p  = (float)pos[t];
  float fr = powf(10000.0f, -(float)i * (1.0f/32.0f));
  float ang = p * fr;
  cosT[idx] = cosf(ang);
  sinT[idx] = sinf(ang);
}

// ---------------- RMSNorm: fp32 in -> bf16 out ----------------
__global__ __launch_bounds__(256) void rmsnorm_k(const float* __restrict__ x,
                                                 const float* __restrict__ wgt,
                                                 unsigned short* __restrict__ out) {
  const long row = blockIdx.x;
  const int t = threadIdx.x;
  f32x4 v = *(const f32x4*)&x[row*D_MODEL + t*4];
  float ss = v[0]*v[0] + v[1]*v[1] + v[2]*v[2] + v[3]*v[3];
  #pragma unroll
  for (int off=1; off<64; off<<=1) ss += __shfl_xor(ss, off, 64);
  __shared__ float red[4];
  if ((t & 63) == 0) red[t >> 6] = ss;
  __syncthreads();
  float tot = red[0] + red[1] + red[2] + red[3];
  float inv = rsqrtf(tot * (1.0f/D_MODEL) + 1e-5f);
  f32x4 wv = *(const f32x4*)&wgt[t*4];
  u16x4 o;
  #pragma unroll
  for (int c=0;c<4;c++) o[c] = f2bf(v[c] * inv * wv[c]);
  *(u16x4*)&out[row*D_MODEL + t*4] = o;
}

// ---------------- RoPE in-place on fused qkv; Q pre-scaled by 1/8 ----------------
__global__ __launch_bounds__(256) void rope_k(unsigned short* __restrict__ qkv,
                                              const float* __restrict__ cosT,
                                              const float* __restrict__ sinT) {
  long idx = (long)blockIdx.x*256 + threadIdx.x;   // NTOK*16*8 exact
  int ig = (int)(idx & 7);
  long th = idx >> 3;
  int h = (int)(th & 15);
  long bt = th >> 4;
  int t = (int)(bt & (SEQ-1));
  long off = bt*QS + h*HEAD_DIM + ig*8;
  f32x4 cs = *(const f32x4*)&cosT[t*32 + ig*4];
  f32x4 sn = *(const f32x4*)&sinT[t*32 + ig*4];
  s16x8 qv = *(const s16x8*)&qkv[off];
  s16x8 kv = *(const s16x8*)&qkv[off + 1024];
  s16x8 qo, ko;
  #pragma unroll
  for (int p=0;p<4;p++) {
    float q1 = bf2f((unsigned short)qv[2*p]), q2 = bf2f((unsigned short)qv[2*p+1]);
    qo[2*p]   = (short)f2bf((q1*cs[p] - q2*sn[p]) * 0.125f);  // fold 1/sqrt(64)
    qo[2*p+1] = (short)f2bf((q1*sn[p] + q2*cs[p]) * 0.125f);
    float k1 = bf2f((unsigned short)kv[2*p]), k2 = bf2f((unsigned short)kv[2*p+1]);
    ko[2*p]   = (short)f2bf(k1*cs[p] - k2*sn[p]);
    ko[2*p+1] = (short)f2bf(k1*sn[p] + k2*cs[p]);
  }
  *(s16x8*)&qkv[off] = qo;
  *(s16x8*)&qkv[off + 1024] = ko;
}

// ---------------- GEMM: 256x128 tile, BK=64, 3-deep pipeline, counted vmcnt ----------------
// T2 (XOR swizzle both sides) + T3 (phase interleave, raw barriers) + T4 (vmcnt(6),
// never 0 in steady state) + T5 (setprio around MFMA). 8 waves (2M x 4N), wave
// tile 128x32. LDS 144KB (3 x 48KB K-tile buffers) -> 1 block/CU, 2 waves/SIMD.
// Race audit: each wave's phase ds_reads return before its compiler-inserted
// lgkmcnt -> before its end barrier -> before any wave stages into the retiring
// buffer. Staged-buffer reads guarded by vmcnt(6/0)-before-barrier.
template<int EPI>
__global__ __launch_bounds__(512, 2) void gemm8p(const unsigned short* __restrict__ A,
                                                 const unsigned short* __restrict__ W,
                                                 unsigned short* __restrict__ Cb,
                                                 float* __restrict__ Cf,
                                                 const float* __restrict__ resid,
                                                 int M, int N, int K) {
  __shared__ __align__(16) unsigned short As[3][256*64];   // 96KB
  __shared__ __align__(16) unsigned short Bs[3][128*64];   // 48KB

  const int nwg = gridDim.x * gridDim.y;
  int orig = blockIdx.y * gridDim.x + blockIdx.x;
  int swz = orig;
  if ((nwg & 7) == 0) { int cpx = nwg >> 3; swz = (orig & 7) * cpx + (orig >> 3); }
  const int bx = swz % gridDim.x;
  const int by = swz / gridDim.x;

  const int tid = threadIdx.x;
  const int wid = tid >> 6;
  const int l  = tid & 63;
  const int lr = l & 15;
  const int lg = l >> 4;
  const int wm = (wid >> 2) * 128;   // 0 / 128
  const int wn = (wid & 3) * 32;     // 0 / 32 / 64 / 96

  const long rowA0 = (long)by * 256;
  const long rowB0 = (long)bx * 128;
  const int nk = K >> 6;

  auto stA = [&](int bf, int kt, int it) {
    int chunk = it*512 + tid;
    int row = chunk >> 3;
    int csw = (chunk & 7) ^ (row & 7);
    gload_lds16(&A[(rowA0 + row)*(long)K + kt + csw*8], &As[bf][chunk*8]);
  };
  auto stB = [&](int bf, int kt, int it) {
    int chunk = it*512 + tid;
    int row = chunk >> 3;
    int csw = (chunk & 7) ^ (row & 7);
    gload_lds16(&W[(rowB0 + row)*(long)K + kt + csw*8], &Bs[bf][chunk*8]);
  };

  f32x4 acc[8][2] = {};

  // prologue: stage tiles 0 and 1; require tile 0 landed (6 newest may fly)
  stA(0,0,0); stA(0,0,1); stA(0,0,2); stA(0,0,3); stB(0,0,0); stB(0,0,1);
  stA(1,64,0); stA(1,64,1); stA(1,64,2); stA(1,64,3); stB(1,64,0); stB(1,64,1);
  asm volatile("s_waitcnt vmcnt(6)" ::: "memory");
  __builtin_amdgcn_s_barrier();

  int buf = 0;
  for (int ki = 0; ki < nk; ++ki) {
    const int sb = (buf >= 1) ? buf - 1 : buf + 2;   // (buf+2)%3
    const int kt2 = (ki + 2) << 6;
    const bool st = (ki + 2) < nk;

    s16x8 af[2][4], bfr[2][2];
    // ---- phase 0: A rows-half 0 + all B frags; stage 3 chunks of tile ki+2 ----
    #pragma unroll
    for (int m=0;m<4;m++) {
      int r = wm + m*16 + lr;
      #pragma unroll
      for (int kk=0;kk<2;kk++)
        af[kk][m] = *(const s16x8*)&As[buf][r*64 + ((kk*4+lg)^(r&7))*8];
    }
    #pragma unroll
    for (int n=0;n<2;n++) {
      int r = wn + n*16 + lr;
      #pragma unroll
      for (int kk=0;kk<2;kk++)
        bfr[kk][n] = *(const s16x8*)&Bs[buf][r*64 + ((kk*4+lg)^(r&7))*8];
    }
    if (st) { stA(sb,kt2,0); stA(sb,kt2,1); stB(sb,kt2,0); }
    __builtin_amdgcn_s_barrier();
    __builtin_amdgcn_s_setprio(1);
    #pragma unroll
    for (int kk=0;kk<2;kk++)
      #pragma unroll
      for (int m=0;m<4;m++)
        #pragma unroll
        for (int n=0;n<2;n++)
          acc[m][n] = __builtin_amdgcn_mfma_f32_16x16x32_bf16(af[kk][m], bfr[kk][n], acc[m][n], 0,0,0);
    __builtin_amdgcn_s_setprio(0);
    __builtin_amdgcn_s_barrier();

    // ---- phase 1: A rows-half 1 (B reused); stage 3; boundary wait ----
    #pragma unroll
    for (int m=0;m<4;m++) {
      int r = wm + 64 + m*16 + lr;
      #pragma unroll
      for (int kk=0;kk<2;kk++)
        af[kk][m] = *(const s16x8*)&As[buf][r*64 + ((kk*4+lg)^(r&7))*8];
    }
    if (st) { stA(sb,kt2,2); stA(sb,kt2,3); stB(sb,kt2,1); }
    __builtin_amdgcn_s_barrier();
    __builtin_amdgcn_s_setprio(1);
    #pragma unroll
    for (int kk=0;kk<2;kk++)
      #pragma unroll
      for (int m=0;m<4;m++)
        #pragma unroll
        for (int n=0;n<2;n++)
          acc[4+m][n] = __builtin_amdgcn_mfma_f32_16x16x32_bf16(af[kk][m], bfr[kk][n], acc[4+m][n], 0,0,0);
    __builtin_amdgcn_s_setprio(0);
    if (st)             { asm volatile("s_waitcnt vmcnt(6)" ::: "memory"); }
    else if (ki+1 < nk) { asm volatile("s_waitcnt vmcnt(0)" ::: "memory"); }
    __builtin_amdgcn_s_barrier();

    buf = (buf == 2) ? 0 : buf + 1;
  }

  #pragma unroll
  for (int mi=0;mi<8;mi++)
    #pragma unroll
    for (int n=0;n<2;n++)
      #pragma unroll
      for (int rr=0;rr<4;rr++) {
        long row = rowA0 + wm + mi*16 + lg*4 + rr;
        long col = rowB0 + wn + n*16 + lr;
        float val = acc[mi][n][rr];
        if constexpr (EPI == 0) {
          Cb[row*(long)N + col] = f2bf(val);
        } else {
          Cf[row*(long)N + col] = resid[row*(long)N + col] + val;
        }
      }
}

// ---------------- Flash attention (causal), unchanged from round 3 ----------------
__global__ __launch_bounds__(256) void attn_k(const unsigned short* __restrict__ QKV,
                                              unsigned short* __restrict__ O) {
  const int bh = blockIdx.x;
  const int b = bh >> 4;
  const int h = bh & 15;
  const int tid = threadIdx.x;
  const int w  = tid >> 6;
  const int l  = tid & 63;
  const int lr = l & 15;
  const int lg = l >> 4;

  const unsigned short* Qp = QKV;
  const unsigned short* Kp = QKV + 1024;
  const unsigned short* Vp = QKV + 2048;

  __shared__ __align__(16) unsigned short Ks[2][64*64];
  __shared__ __align__(16) unsigned short Vs[2][64*64];
  __shared__ __align__(16) unsigned short Ps[4][16][64];

  const int skv = tid >> 2;
  const int sd0 = (tid & 3) * 16;
  const long hbase = (long)(b*SEQ)*QS + h*HEAD_DIM;

  for (int pass = 0; pass < 2; ++pass) {
    const int qt = pass ? 31 - (int)blockIdx.y : (int)blockIdx.y;
    const int q0 = qt * 64;
    const int ntile = qt + 1;

    const long rowQ = (long)(b*SEQ + q0 + w*16 + lr);
    s16x8 qf0 = *(const s16x8*)&Qp[rowQ*QS + h*HEAD_DIM + lg*8];
    s16x8 qf1 = *(const s16x8*)&Qp[rowQ*QS + h*HEAD_DIM + 32 + lg*8];

    float mi = -1e30f, li = 0.f;
    f32x4 oa[4] = {};

    #pragma unroll
    for (int it=0; it<2; ++it) {
      int chunk = it*256 + tid;
      int row = chunk >> 3;
      int csw = (chunk & 7) ^ (row & 7);
      gload_lds16(&Kp[hbase + (long)row*QS + csw*8], &Ks[0][chunk*8]);
    }
    {
      const unsigned short* src = &Vp[hbase + (long)skv*QS + sd0];
      s16x8 v0 = *(const s16x8*)&src[0];
      s16x8 v1 = *(const s16x8*)&src[8];
      #pragma unroll
      for (int i=0;i<16;i++) {
        int d = sd0 + i;
        int key = (d&7) ^ ((d>>3)&7);
        int c = (skv>>3) ^ key;
        Vs[0][d*64 + c*8 + (skv&7)] = (unsigned short)(i<8 ? v0[i] : v1[i-8]);
      }
    }
    __syncthreads();

    for (int t=0; t<ntile; ++t) {
      const int kv0 = t*64;
      const int cur = t & 1;
      const int nb  = cur ^ 1;
      const bool more = (t+1 < ntile);

      s16x8 v0, v1;
      if (more) {
        #pragma unroll
        for (int it=0; it<2; ++it) {
          int chunk = it*256 + tid;
          int row = chunk >> 3;
          int csw = (chunk & 7) ^ (row & 7);
          gload_lds16(&Kp[hbase + (long)(kv0 + 64 + row)*QS + csw*8], &Ks[nb][chunk*8]);
        }
        const unsigned short* src = &Vp[hbase + (long)(kv0 + 64 + skv)*QS + sd0];
        v0 = *(const s16x8*)&src[0];
        v1 = *(const s16x8*)&src[8];
      }

      f32x4 s[4];
      __builtin_amdgcn_s_setprio(1);
      #pragma unroll
      for (int j=0;j<4;j++) {
        int krow = j*16 + lr;
        s16x8 kf0 = *(const s16x8*)&Ks[cur][krow*64 + ((lg)     ^ (krow&7))*8];
        s16x8 kf1 = *(const s16x8*)&Ks[cur][krow*64 + ((4 + lg) ^ (krow&7))*8];
        f32x4 acc = {};
        acc = __builtin_amdgcn_mfma_f32_16x16x32_bf16(kf0, qf0, acc, 0,0,0);
        acc = __builtin_amdgcn_mfma_f32_16x16x32_bf16(kf1, qf1, acc, 0,0,0);
        s[j] = acc;
      }
      __builtin_amdgcn_s_setprio(0);

      if (t == ntile-1) {
        #pragma unroll
        for (int j=0;j<4;j++)
          #pragma unroll
          for (int r=0;r<4;r++)
            if (kv0 + j*16 + lg*4 + r > q0 + w*16 + lr) s[j][r] = -1e30f;
      }

      float pmax = s[0][0];
      #pragma unroll
      for (int j=0;j<4;j++)
        #pragma unroll
        for (int r=0;r<4;r++) pmax = fmaxf(pmax, s[j][r]);
      pmax = fmaxf(pmax, __shfl_xor(pmax, 16, 64));
      pmax = fmaxf(pmax, __shfl_xor(pmax, 32, 64));
      float mn = fmaxf(mi, pmax);
      float al = __expf(mi - mn);
      mi = mn;
      float psum = 0.f;
      #pragma unroll
      for (int j=0;j<4;j++)
        #pragma unroll
        for (int r=0;r<4;r++) {
          float p = __expf(s[j][r] - mn);
          s[j][r] = p;
          psum += p;
        }
      psum += __shfl_xor(psum, 16, 64);
      psum += __shfl_xor(psum, 32, 64);
      li = li*al + psum;

      float alq[4];
      #pragma unroll
      for (int r=0;r<4;r++) alq[r] = __shfl(al, lg*4 + r, 64);
      #pragma unroll
      for (int d=0;d<4;d++)
        #pragma unroll
        for (int r=0;r<4;r++) oa[d][r] *= alq[r];

      #pragma unroll
      for (int j=0;j<4;j++)
        #pragma unroll
        for (int r=0;r<4;r++) {
          int k = j*16 + lg*4 + r;
          int pos = ((k>>3) ^ (lr&7))*8 + (k&7);
          Ps[w][lr][pos] = f2bf(s[j][r]);
        }

      if (more) {
        #pragma unroll
        for (int i=0;i<16;i++) {
          int d = sd0 + i;
          int key = (d&7) ^ ((d>>3)&7);
          int c = (skv>>3) ^ key;
          Vs[nb][d*64 + c*8 + (skv&7)] = (unsigned short)(i<8 ? v0[i] : v1[i-8]);
        }
      }

      __builtin_amdgcn_s_setprio(1);
      #pragma unroll
      for (int kk=0;kk<2;kk++) {
        s16x8 pa = *(const s16x8*)&Ps[w][lr][((kk*4 + lg) ^ (lr&7))*8];
        #pragma unroll
        for (int d=0;d<4;d++) {
          int vrow = d*16 + lr;
          int key = (vrow&7) ^ ((vrow>>3)&7);
          int c = (kk*4 + lg) ^ key;
          s16x8 vb = *(const s16x8*)&Vs[cur][vrow*64 + c*8];
          oa[d] = __builtin_amdgcn_mfma_f32_16x16x32_bf16(pa, vb, oa[d], 0,0,0);
        }
      }
      __builtin_amdgcn_s_setprio(0);
      __syncthreads();
    }

    float liq[4];
    #pragma unroll
    for (int r=0;r<4;r++) liq[r] = __shfl(li, lg*4 + r, 64);
    #pragma unroll
    for (int d=0;d<4;d++)
      #pragma unroll
      for (int r=0;r<4;r++) {
        long row = (long)(b*SEQ + q0 + w*16 + lg*4 + r);
        O[row*D_MODEL + h*HEAD_DIM + d*16 + lr] = f2bf(oa[d][r] / liq[r]);
      }
  }
}

// ---------------- SwiGLU ----------------
__global__ __launch_bounds__(256) void swiglu_k(unsigned short* __restrict__ a,
                                                const unsigned short* __restrict__ g) {
  long i = ((long)blockIdx.x*256 + threadIdx.x)*8;
  s16x8 av = *(const s16x8*)&a[i];
  s16x8 gv = *(const s16x8*)&g[i];
  s16x8 o;
  #pragma unroll
  for (int c=0;c<8;c++) {
    float xx = bf2f((unsigned short)av[c]);
    float yy = bf2f((unsigned short)gv[c]);
    float sg = 1.0f / (1.0f + __expf(-xx));
    o[c] = (short)f2bf(xx * sg * yy);
  }
  *(s16x8*)&a[i] = o;
}

extern "C" void kernel_launch(void* const* d_in, const int* in_sizes, int n_in,
                              void* d_out, int out_size, void* d_ws, size_t ws_size,
                              hipStream_t stream) {
  (void)in_sizes; (void)n_in; (void)out_size; (void)ws_size;
  const float* x    = (const float*)d_in[0];
  const int*   tpos = (const int*)d_in[1];
  const float* ln1  = (const float*)d_in[2];
  const float* qw   = (const float*)d_in[3];
  const float* kw   = (const float*)d_in[4];
  const float* vw   = (const float*)d_in[5];
  const float* ow   = (const float*)d_in[6];
  const float* ln2  = (const float*)d_in[7];
  const float* w1   = (const float*)d_in[8];
  const float* w2   = (const float*)d_in[9];
  const float* w3   = (const float*)d_in[10];
  float* out = (float*)d_out;

  char* ws = (char*)d_ws;
  size_t off = 0;
  auto nalloc = [&](size_t b) { void* p = ws + off; off += (b + 255) & ~(size_t)255; return p; };

  unsigned short* wqkvb = (unsigned short*)nalloc((size_t)3072*D_MODEL*2);
  unsigned short* wob   = (unsigned short*)nalloc((size_t)D_MODEL*D_MODEL*2);
  unsigned short* w1b   = (unsigned short*)nalloc((size_t)D_FF*D_MODEL*2);
  unsigned short* w3b   = (unsigned short*)nalloc((size_t)D_FF*D_MODEL*2);
  unsigned short* w2b   = (unsigned short*)nalloc((size_t)D_MODEL*D_FF*2);
  float* cosT = (float*)nalloc((size_t)SEQ*32*4);
  float* sinT = (float*)nalloc((size_t)SEQ*32*4);
  unsigned short* hbuf = (unsigned short*)nalloc((size_t)NTOK*D_MODEL*2);
  unsigned short* qkv  = (unsigned short*)nalloc((size_t)NTOK*QS*2);      // 48MB
  unsigned short* ctxb = (unsigned short*)nalloc((size_t)NTOK*D_MODEL*2); // 16MB, adjacent
  float* x2 = (float*)nalloc((size_t)NTOK*D_MODEL*4);
  unsigned short* gbuf = (unsigned short*)nalloc((size_t)NTOK*D_FF*2);
  unsigned short* abuf = qkv;   // qkv..ctxb span = exactly NTOK*D_FF bf16, free after O-proj

  cvt_all_k<<<16384,256,0,stream>>>(qw, kw, vw, ow, w1, w2, w3,
                                    wqkvb, wob, w1b, w2b, w3b);
  rope_tables_k<<<SEQ*32/256,256,0,stream>>>(tpos, cosT, sinT);

  rmsnorm_k<<<NTOK,256,0,stream>>>(x, ln1, hbuf);
  gemm8p<0><<<dim3(24,32),512,0,stream>>>(hbuf, wqkvb, qkv, nullptr, nullptr, NTOK, QS, D_MODEL);
  rope_k<<<4096,256,0,stream>>>(qkv, cosT, sinT);
  attn_k<<<dim3(64,16),256,0,stream>>>(qkv, ctxb);
  gemm8p<1><<<dim3(8,32),512,0,stream>>>(ctxb, wob, nullptr, x2, x, NTOK, D_MODEL, D_MODEL);

  rmsnorm_k<<<NTOK,256,0,stream>>>(x2, ln2, hbuf);
  gemm8p<0><<<dim3(32,32),512,0,stream>>>(hbuf, w1b, abuf, nullptr, nullptr, NTOK, D_FF, D_MODEL);
  gemm8p<0><<<dim3(32,32),512,0,stream>>>(hbuf, w3b, gbuf, nullptr, nullptr, NTOK, D_FF, D_MODEL);
  swiglu_k<<<(long)NTOK*D_FF/8/256,256,0,stream>>>(abuf, gbuf);
  gemm8p<1><<<dim3(8,32),512,0,stream>>>(abuf, w2b, nullptr, out, x2, NTOK, D_MODEL, D_FF);
}